// Round 1
// baseline (1069.550 us; speedup 1.0000x reference)
//
#include <hip/hip_runtime.h>

#define NG 8   // graphs

// ---------------- CSR build ----------------

__global__ __launch_bounds__(256)
void k_deg(const int* __restrict__ dst, int* __restrict__ deg, int E) {
    int i = blockIdx.x * 256 + threadIdx.x;
    if (i < E) atomicAdd(&deg[dst[i]], 1);
}

__global__ __launch_bounds__(1024)
void k_scan_a(const int* __restrict__ deg, int* __restrict__ incl,
              int* __restrict__ bsum, int n) {
    __shared__ int s[1024];
    int t = threadIdx.x;
    int base = blockIdx.x * 1024;
    int v = (base + t < n) ? deg[base + t] : 0;
    s[t] = v;
    __syncthreads();
    for (int off = 1; off < 1024; off <<= 1) {
        int x = 0;
        if (t >= off) x = s[t - off];
        __syncthreads();
        if (t >= off) s[t] += x;
        __syncthreads();
    }
    if (base + t < n) incl[base + t] = s[t];
    if (t == 1023) bsum[blockIdx.x] = s[1023];
}

__global__ void k_scan_b(int* bsum, int nb) {
    if (threadIdx.x == 0 && blockIdx.x == 0) {
        int run = 0;
        for (int i = 0; i < nb; ++i) { int v = bsum[i]; bsum[i] = run; run += v; }
    }
}

__global__ __launch_bounds__(256)
void k_scan_c(const int* __restrict__ incl, const int* __restrict__ deg,
              const int* __restrict__ bsum, int* __restrict__ rowp, int n) {
    int i = blockIdx.x * 256 + threadIdx.x;
    if (i < n) rowp[i] = incl[i] - deg[i] + bsum[i >> 10];
}

__global__ __launch_bounds__(256)
void k_scatter(const int* __restrict__ src, const int* __restrict__ dst,
               const int* __restrict__ rowp, int* __restrict__ cur,
               int* __restrict__ ss, int E) {
    int i = blockIdx.x * 256 + threadIdx.x;
    if (i < E) {
        int d = dst[i];
        int pos = rowp[d] + atomicAdd(&cur[d], 1);
        ss[pos] = src[i];
    }
}

// ---------------- aggregation: z = (1+eps)*h + sum_{u in N(v)} h[u] ----------------

template<int D>
__global__ __launch_bounds__(256)
void k_agg(const float* __restrict__ h, const int* __restrict__ rowp,
           const int* __restrict__ deg, const int* __restrict__ ss,
           const float* __restrict__ eps, float* __restrict__ z, int n) {
    constexpr int TPN = D / 4;       // threads per node (float4 lanes)
    constexpr int NPB = 256 / TPN;   // nodes per block
    int node = blockIdx.x * NPB + threadIdx.x / TPN;
    int lane = threadIdx.x % TPN;
    if (node >= n) return;
    float e1 = 1.0f + eps[0];
    size_t base = (size_t)node * D + lane * 4;
    float4 v = *(const float4*)(h + base);
    float4 acc;
    acc.x = v.x * e1; acc.y = v.y * e1; acc.z = v.z * e1; acc.w = v.w * e1;
    int s  = rowp[node];
    int dn = deg[node];
    for (int j = 0; j < dn; ++j) {
        int u = ss[s + j];
        const float4 hv = *(const float4*)(h + (size_t)u * D + lane * 4);
        acc.x += hv.x; acc.y += hv.y; acc.z += hv.z; acc.w += hv.w;
    }
    *(float4*)(z + base) = acc;
}

// ---------------- GEMM: C[n][m] = (relu)(sum_k A[n][k]*W[m][k] + bias[m]) ----------------
// A: [n x K] row-major, W: [M x K] row-major. BM=BN=64, BK=32, 256 thr, 4x4 micro-tile.

template<bool RELU>
__global__ __launch_bounds__(256)
void k_gemm(const float* __restrict__ A, const float* __restrict__ W,
            const float* __restrict__ bias, float* __restrict__ C,
            int n, int K, int M) {
    constexpr int BM = 64, BN = 64, BK = 32;
    __shared__ float As[BK][BM + 4];
    __shared__ float Ws[BK][BN + 4];
    int tid  = threadIdx.x;
    int brow = blockIdx.x * BM;
    int bcol = blockIdx.y * BN;
    int tr = tid >> 4, tc = tid & 15;
    float acc[4][4];
#pragma unroll
    for (int i = 0; i < 4; ++i)
#pragma unroll
        for (int j = 0; j < 4; ++j) acc[i][j] = 0.0f;

    for (int k0 = 0; k0 < K; k0 += BK) {
#pragma unroll
        for (int m = 0; m < 2; ++m) {
            int lin = tid + m * 256;
            int r   = lin >> 3;
            int kk  = (lin & 7) << 2;
            int gr  = brow + r; if (gr > n - 1) gr = n - 1;
            const float4 av = *(const float4*)(A + (size_t)gr * K + k0 + kk);
            As[kk + 0][r] = av.x; As[kk + 1][r] = av.y;
            As[kk + 2][r] = av.z; As[kk + 3][r] = av.w;
            const float4 wv = *(const float4*)(W + (size_t)(bcol + r) * K + k0 + kk);
            Ws[kk + 0][r] = wv.x; Ws[kk + 1][r] = wv.y;
            Ws[kk + 2][r] = wv.z; Ws[kk + 3][r] = wv.w;
        }
        __syncthreads();
#pragma unroll
        for (int kk = 0; kk < BK; ++kk) {
            float4 a = *(const float4*)&As[kk][tr << 2];
            float4 b = *(const float4*)&Ws[kk][tc << 2];
            acc[0][0] += a.x * b.x; acc[0][1] += a.x * b.y; acc[0][2] += a.x * b.z; acc[0][3] += a.x * b.w;
            acc[1][0] += a.y * b.x; acc[1][1] += a.y * b.y; acc[1][2] += a.y * b.z; acc[1][3] += a.y * b.w;
            acc[2][0] += a.z * b.x; acc[2][1] += a.z * b.y; acc[2][2] += a.z * b.z; acc[2][3] += a.z * b.w;
            acc[3][0] += a.w * b.x; acc[3][1] += a.w * b.y; acc[3][2] += a.w * b.z; acc[3][3] += a.w * b.w;
        }
        __syncthreads();
    }
    float4 bv = *(const float4*)(bias + bcol + (tc << 2));
#pragma unroll
    for (int i = 0; i < 4; ++i) {
        int row = brow + (tr << 2) + i;
        if (row < n) {
            float4 o;
            o.x = acc[i][0] + bv.x; o.y = acc[i][1] + bv.y;
            o.z = acc[i][2] + bv.z; o.w = acc[i][3] + bv.w;
            if (RELU) {
                o.x = fmaxf(o.x, 0.0f); o.y = fmaxf(o.y, 0.0f);
                o.z = fmaxf(o.z, 0.0f); o.w = fmaxf(o.w, 0.0f);
            }
            *(float4*)(C + (size_t)row * M + bcol + (tc << 2)) = o;
        }
    }
}

// ---------------- BatchNorm ----------------

__global__ __launch_bounds__(256)
void k_bnstats(const float* __restrict__ z, float* __restrict__ stats, int n, int M) {
    int rpb = 256 / M;                 // rows handled concurrently per block
    int col = threadIdx.x % M;
    int ro  = threadIdx.x / M;
    float s = 0.0f, s2 = 0.0f;
    for (int r = blockIdx.x * rpb + ro; r < n; r += gridDim.x * rpb) {
        float v = z[(size_t)r * M + col];
        s += v; s2 += v * v;
    }
    atomicAdd(&stats[col], s);
    atomicAdd(&stats[M + col], s2);
}

__global__ void k_bnprep(float* __restrict__ stats, const float* __restrict__ gamma,
                         const float* __restrict__ beta, int n, int M) {
    int c = threadIdx.x;
    if (c < M) {
        float invN = 1.0f / (float)n;
        float mean = stats[c] * invN;
        float var  = stats[M + c] * invN - mean * mean;
        float sc   = rsqrtf(var + 1e-5f) * gamma[c];
        stats[2 * M + c] = sc;
        stats[3 * M + c] = beta[c] - mean * sc;
    }
}

template<bool RELU>
__global__ __launch_bounds__(256)
void k_bnapply(const float* __restrict__ z, const float* __restrict__ stats,
               float* __restrict__ h, int n, int M) {
    const float* scale = stats + 2 * M;
    const float* shift = stats + 3 * M;
    int total4 = n * (M / 4);
    for (int i = blockIdx.x * 256 + threadIdx.x; i < total4; i += gridDim.x * 256) {
        int c = (i << 2) % M;
        float4 v  = *(const float4*)(z + (size_t)i * 4);
        float4 sc = *(const float4*)(scale + c);
        float4 sh = *(const float4*)(shift + c);
        float4 o;
        o.x = v.x * sc.x + sh.x; o.y = v.y * sc.y + sh.y;
        o.z = v.z * sc.z + sh.z; o.w = v.w * sc.w + sh.w;
        if (RELU) {
            o.x = fmaxf(o.x, 0.0f); o.y = fmaxf(o.y, 0.0f);
            o.z = fmaxf(o.z, 0.0f); o.w = fmaxf(o.w, 0.0f);
        }
        *(float4*)(h + (size_t)i * 4) = o;
    }
}

// ---------------- graph readout ----------------

__global__ __launch_bounds__(256)
void k_readout(const float* __restrict__ h, const int* __restrict__ gid,
               float* __restrict__ gsum, int* __restrict__ gcnt, int n) {
    __shared__ float ls[NG * 128];
    __shared__ int   lc[NG];
    for (int i = threadIdx.x; i < NG * 128; i += 256) ls[i] = 0.0f;
    if (threadIdx.x < NG) lc[threadIdx.x] = 0;
    __syncthreads();
    int c  = threadIdx.x & 127;
    int ro = threadIdx.x >> 7;   // 0 or 1
    for (int r = blockIdx.x * 2 + ro; r < n; r += gridDim.x * 2) {
        int g = gid[r];
        atomicAdd(&ls[g * 128 + c], h[(size_t)r * 128 + c]);
        if (c == 0) atomicAdd(&lc[g], 1);
    }
    __syncthreads();
    for (int i = threadIdx.x; i < NG * 128; i += 256) atomicAdd(&gsum[i], ls[i]);
    if (threadIdx.x < NG) atomicAdd(&gcnt[threadIdx.x], lc[threadIdx.x]);
}

__global__ void k_final(const float* __restrict__ gsum, const int* __restrict__ gcnt,
                        float* __restrict__ out) {
    int i = blockIdx.x * 256 + threadIdx.x;
    if (i < NG * 128) {
        int g = i >> 7;
        out[i] = gsum[i] / fmaxf((float)gcnt[g], 1.0f);
    }
}

// ---------------- host ----------------

extern "C" void kernel_launch(void* const* d_in, const int* in_sizes, int n_in,
                              void* d_out, int out_size, void* d_ws, size_t ws_size,
                              hipStream_t stream) {
    const float* x   = (const float*)d_in[0];
    const int*   src = (const int*)d_in[1];
    const int*   dst = (const int*)d_in[2];
    const int*   gid = (const int*)d_in[3];
    const int n = in_sizes[0] / 128;
    const int E = in_sizes[1];

    auto align = [](size_t o) { return (o + 255) & ~(size_t)255; };
    char* ws = (char*)d_ws;
    size_t off = 0;
    const size_t SZ_P = align((size_t)n * 256 * sizeof(float));
    const size_t SZ_I = align((size_t)n * sizeof(int));

    float* P0   = (float*)(ws + off); off += SZ_P;
    float* P1   = (float*)(ws + off); off += SZ_P;
    float* P2   = (float*)(ws + off); off += SZ_P;
    int*   deg  = (int*)(ws + off);   off += SZ_I;
    int*   incl = (int*)(ws + off);   off += SZ_I;
    int*   rowp = (int*)(ws + off);   off += SZ_I;
    int*   cur  = (int*)(ws + off);   off += SZ_I;
    int*   bsum = (int*)(ws + off);   off += 256 * sizeof(int);
    int*   ss   = (int*)(ws + off);   off += align((size_t)E * sizeof(int));
    float* stats= (float*)(ws + off); off += align(4 * 256 * sizeof(float));
    float* gsum = (float*)(ws + off); off += align(NG * 128 * sizeof(float));
    int*   gcnt = (int*)(ws + off);   off += 256;

    // ---- CSR build (dst-keyed) ----
    hipMemsetAsync(deg, 0, (size_t)n * sizeof(int), stream);
    k_deg<<<(E + 255) / 256, 256, 0, stream>>>(dst, deg, E);
    int nb = (n + 1023) / 1024;
    k_scan_a<<<nb, 1024, 0, stream>>>(deg, incl, bsum, n);
    k_scan_b<<<1, 1, 0, stream>>>(bsum, nb);
    k_scan_c<<<(n + 255) / 256, 256, 0, stream>>>(incl, deg, bsum, rowp, n);
    hipMemsetAsync(cur, 0, (size_t)n * sizeof(int), stream);
    k_scatter<<<(E + 255) / 256, 256, 0, stream>>>(src, dst, rowp, cur, ss, E);

    // ---- layers ----
    // layer dims: (K=d_in, Mid=d_mid, Mout=d_out)
    const int Ks[3]   = {128, 256, 256};
    const int Mids[3] = {256, 256, 128};
    const int Mouts[3]= {256, 256, 128};

    const float* hin = x;
    for (int L = 0; L < 3; ++L) {
        const int base = 4 + 7 * L;
        const float* w1    = (const float*)d_in[base + 0];
        const float* b1    = (const float*)d_in[base + 1];
        const float* w2    = (const float*)d_in[base + 2];
        const float* b2    = (const float*)d_in[base + 3];
        const float* eps   = (const float*)d_in[base + 4];
        const float* gamma = (const float*)d_in[base + 5];
        const float* beta  = (const float*)d_in[base + 6];
        const int K = Ks[L], Mid = Mids[L], Mout = Mouts[L];

        // agg: hin[n x K] -> P1
        if (K == 128) k_agg<128><<<(n + 7) / 8, 256, 0, stream>>>(hin, rowp, deg, ss, eps, P1, n);
        else          k_agg<256><<<(n + 3) / 4, 256, 0, stream>>>(hin, rowp, deg, ss, eps, P1, n);

        // mlp
        dim3 g1((n + 63) / 64, Mid / 64);
        k_gemm<true><<<g1, 256, 0, stream>>>(P1, w1, b1, P2, n, K, Mid);
        dim3 g2((n + 63) / 64, Mout / 64);
        k_gemm<false><<<g2, 256, 0, stream>>>(P2, w2, b2, P1, n, Mid, Mout);

        // batchnorm (+ relu between layers)
        hipMemsetAsync(stats, 0, 2 * (size_t)Mout * sizeof(float), stream);
        k_bnstats<<<256, 256, 0, stream>>>(P1, stats, n, Mout);
        k_bnprep<<<1, Mout, 0, stream>>>(stats, gamma, beta, n, Mout);
        if (L < 2) k_bnapply<true ><<<2048, 256, 0, stream>>>(P1, stats, P0, n, Mout);
        else       k_bnapply<false><<<2048, 256, 0, stream>>>(P1, stats, P0, n, Mout);

        hin = P0;
    }

    // ---- readout: per-graph mean over nodes ----
    hipMemsetAsync(gsum, 0, NG * 128 * sizeof(float) + 32, stream);
    // gcnt sits right after gsum? ensure separate memset for safety:
    hipMemsetAsync(gcnt, 0, NG * sizeof(int), stream);
    k_readout<<<256, 256, 0, stream>>>(P0, gid, gsum, gcnt, n);
    k_final<<<4, 256, 0, stream>>>(gsum, gcnt, (float*)d_out);
}

// Round 2
// 772.365 us; speedup vs baseline: 1.3848x; 1.3848x over previous
//
#include <hip/hip_runtime.h>

#define NG 8   // graphs

typedef _Float16 half8 __attribute__((ext_vector_type(8)));
typedef _Float16 half2v __attribute__((ext_vector_type(2)));
typedef float    f32x4 __attribute__((ext_vector_type(4)));

// ---------------- casts ----------------

__global__ __launch_bounds__(256)
void k_cast16(const float* __restrict__ in, _Float16* __restrict__ out, int n8) {
    int i = blockIdx.x * 256 + threadIdx.x;
    if (i < n8) {
        const float4 a = *(const float4*)(in + (size_t)i * 8);
        const float4 b = *(const float4*)(in + (size_t)i * 8 + 4);
        half8 o;
        o[0] = (_Float16)a.x; o[1] = (_Float16)a.y; o[2] = (_Float16)a.z; o[3] = (_Float16)a.w;
        o[4] = (_Float16)b.x; o[5] = (_Float16)b.y; o[6] = (_Float16)b.z; o[7] = (_Float16)b.w;
        *(half8*)(out + (size_t)i * 8) = o;
    }
}

// ---------------- CSR build ----------------

__global__ __launch_bounds__(256)
void k_deg(const int* __restrict__ dst, int* __restrict__ deg, int E) {
    int i = blockIdx.x * 256 + threadIdx.x;
    if (i < E) atomicAdd(&deg[dst[i]], 1);
}

__global__ __launch_bounds__(1024)
void k_scan_a(const int* __restrict__ deg, int* __restrict__ incl,
              int* __restrict__ bsum, int n) {
    __shared__ int s[1024];
    int t = threadIdx.x;
    int base = blockIdx.x * 1024;
    int v = (base + t < n) ? deg[base + t] : 0;
    s[t] = v;
    __syncthreads();
    for (int off = 1; off < 1024; off <<= 1) {
        int x = 0;
        if (t >= off) x = s[t - off];
        __syncthreads();
        if (t >= off) s[t] += x;
        __syncthreads();
    }
    if (base + t < n) incl[base + t] = s[t];
    if (t == 1023) bsum[blockIdx.x] = s[1023];
}

__global__ void k_scan_b(int* bsum, int nb) {
    if (threadIdx.x == 0 && blockIdx.x == 0) {
        int run = 0;
        for (int i = 0; i < nb; ++i) { int v = bsum[i]; bsum[i] = run; run += v; }
    }
}

__global__ __launch_bounds__(256)
void k_scan_c(const int* __restrict__ incl, const int* __restrict__ deg,
              const int* __restrict__ bsum, int* __restrict__ rowp, int n) {
    int i = blockIdx.x * 256 + threadIdx.x;
    if (i < n) rowp[i] = incl[i] - deg[i] + bsum[i >> 10];
}

__global__ __launch_bounds__(256)
void k_scatter(const int* __restrict__ src, const int* __restrict__ dst,
               const int* __restrict__ rowp, int* __restrict__ cur,
               int* __restrict__ ss, int E) {
    int i = blockIdx.x * 256 + threadIdx.x;
    if (i < E) {
        int d = dst[i];
        int pos = rowp[d] + atomicAdd(&cur[d], 1);
        ss[pos] = src[i];
    }
}

// ---------------- aggregation (fp16 rows, fp32 accum) ----------------

template<int K>
__global__ __launch_bounds__(256)
void k_agg16(const _Float16* __restrict__ h, const int* __restrict__ rowp,
             const int* __restrict__ deg, const int* __restrict__ ss,
             const float* __restrict__ eps, _Float16* __restrict__ z, int n) {
    constexpr int TPN = K / 8;       // threads per node (16B lanes)
    constexpr int NPB = 256 / TPN;
    int node = blockIdx.x * NPB + threadIdx.x / TPN;
    int lane = threadIdx.x % TPN;
    if (node >= n) return;
    float e1 = 1.0f + eps[0];
    size_t base = (size_t)node * K + lane * 8;
    half8 v = *(const half8*)(h + base);
    float a[8];
#pragma unroll
    for (int i = 0; i < 8; ++i) a[i] = (float)v[i] * e1;
    int s  = rowp[node];
    int dn = deg[node];
    int j = 0;
    for (; j + 2 <= dn; j += 2) {
        int u0 = ss[s + j], u1 = ss[s + j + 1];
        half8 h0 = *(const half8*)(h + (size_t)u0 * K + lane * 8);
        half8 h1 = *(const half8*)(h + (size_t)u1 * K + lane * 8);
#pragma unroll
        for (int i = 0; i < 8; ++i) a[i] += (float)h0[i] + (float)h1[i];
    }
    if (j < dn) {
        int u = ss[s + j];
        half8 hv = *(const half8*)(h + (size_t)u * K + lane * 8);
#pragma unroll
        for (int i = 0; i < 8; ++i) a[i] += (float)hv[i];
    }
    half8 o;
#pragma unroll
    for (int i = 0; i < 8; ++i) o[i] = (_Float16)a[i];
    *(half8*)(z + base) = o;
}

// ---------------- MFMA GEMM: C = (relu)(A @ W^T + bias) ----------------
// A: [n x K] fp16 row-major; W: [M x K] fp16 row-major (already B^T layout).
// 128x128 tile, BK=64, 256 threads (4 waves, 2x2 of 64x64).
// LDS tiles [128 rows][64 k] fp16 with XOR swizzle: kbyte ^= (row&7)<<4.

template<bool RELU>
__global__ __launch_bounds__(256)
void k_gemm16(const _Float16* __restrict__ A, const _Float16* __restrict__ W,
              const float* __restrict__ bias, _Float16* __restrict__ C,
              int n, int K, int M) {
    constexpr int BM = 128, BK = 64;
    __shared__ char As[BM * BK * 2];
    __shared__ char Bs[BM * BK * 2];
    const int tid  = threadIdx.x;
    const int lane = tid & 63;
    const int wid  = tid >> 6;
    const int wr   = wid >> 1, wc = wid & 1;
    const int brow = blockIdx.x * BM;
    const int bcol = blockIdx.y * BM;

    // staging geometry: per issue i (0..3), 256 threads cover rows i*32..i*32+31, 8x16B per row
    const int srow = tid >> 3;          // 0..31
    const int spk  = (tid & 7) << 4;    // phys kbyte in row (0..112)

    f32x4 acc[4][4];
#pragma unroll
    for (int m = 0; m < 4; ++m)
#pragma unroll
        for (int nn = 0; nn < 4; ++nn) acc[m][nn] = (f32x4){0.f, 0.f, 0.f, 0.f};

    uint4 ar[4], br[4];
    const int nk = K / BK;

    // prefetch k0 = 0
#pragma unroll
    for (int i = 0; i < 4; ++i) {
        int row = i * 32 + srow;
        int lk  = spk ^ ((row & 7) << 4);            // logical kbyte for this phys slot
        int ga  = brow + row; if (ga > n - 1) ga = n - 1;
        ar[i] = *(const uint4*)((const char*)A + ((size_t)ga * K) * 2 + lk);
        br[i] = *(const uint4*)((const char*)W + ((size_t)(bcol + row) * K) * 2 + lk);
    }

    for (int t = 0; t < nk; ++t) {
        __syncthreads();   // prior reads done before overwrite
#pragma unroll
        for (int i = 0; i < 4; ++i) {
            int row = i * 32 + srow;
            *(uint4*)(As + row * 128 + spk) = ar[i];
            *(uint4*)(Bs + row * 128 + spk) = br[i];
        }
        __syncthreads();
        if (t + 1 < nk) {
            int k0 = (t + 1) * BK;
#pragma unroll
            for (int i = 0; i < 4; ++i) {
                int row = i * 32 + srow;
                int lk  = spk ^ ((row & 7) << 4);
                int ga  = brow + row; if (ga > n - 1) ga = n - 1;
                ar[i] = *(const uint4*)((const char*)A + ((size_t)ga * K + k0) * 2 + lk);
                br[i] = *(const uint4*)((const char*)W + ((size_t)(bcol + row) * K + k0) * 2 + lk);
            }
        }
#pragma unroll
        for (int kk = 0; kk < 2; ++kk) {
            const int kb = kk * 64 + (lane >> 4) * 16;   // logical kbyte of this lane's 8 halves
            half8 af[4], bf[4];
#pragma unroll
            for (int m = 0; m < 4; ++m) {
                int rowA = wr * 64 + m * 16 + (lane & 15);
                af[m] = *(const half8*)(As + rowA * 128 + (kb ^ ((rowA & 7) << 4)));
                int rowB = wc * 64 + m * 16 + (lane & 15);
                bf[m] = *(const half8*)(Bs + rowB * 128 + (kb ^ ((rowB & 7) << 4)));
            }
#pragma unroll
            for (int m = 0; m < 4; ++m)
#pragma unroll
                for (int nn = 0; nn < 4; ++nn)
                    acc[m][nn] = __builtin_amdgcn_mfma_f32_16x16x32_f16(af[m], bf[nn], acc[m][nn], 0, 0, 0);
        }
    }

    // epilogue: D lane mapping col = lane&15, row = (lane>>4)*4 + j
#pragma unroll
    for (int nn = 0; nn < 4; ++nn) {
        const int col = bcol + wc * 64 + nn * 16 + (lane & 15);
        const float bb = bias[col];
#pragma unroll
        for (int m = 0; m < 4; ++m) {
#pragma unroll
            for (int j = 0; j < 4; ++j) {
                int row = brow + wr * 64 + m * 16 + (lane >> 4) * 4 + j;
                if (row < n) {
                    float v = acc[m][nn][j] + bb;
                    if (RELU) v = fmaxf(v, 0.0f);
                    C[(size_t)row * M + col] = (_Float16)v;
                }
            }
        }
    }
}

// ---------------- BatchNorm ----------------

__global__ __launch_bounds__(256)
void k_bnstats16(const _Float16* __restrict__ z, float* __restrict__ stats, int n, int M) {
    int halfM = M >> 1;
    int col = (threadIdx.x % halfM) << 1;
    int ro  = threadIdx.x / halfM;
    int rpb = 256 / halfM;
    float s0 = 0, s1 = 0, q0 = 0, q1 = 0;
    for (int r = blockIdx.x * rpb + ro; r < n; r += gridDim.x * rpb) {
        half2v v = *(const half2v*)(z + (size_t)r * M + col);
        float a = (float)v[0], b = (float)v[1];
        s0 += a; s1 += b; q0 += a * a; q1 += b * b;
    }
    atomicAdd(&stats[col], s0);
    atomicAdd(&stats[col + 1], s1);
    atomicAdd(&stats[M + col], q0);
    atomicAdd(&stats[M + col + 1], q1);
}

__global__ void k_bnprep(float* __restrict__ stats, const float* __restrict__ gamma,
                         const float* __restrict__ beta, int n, int M) {
    int c = threadIdx.x;
    if (c < M) {
        float invN = 1.0f / (float)n;
        float mean = stats[c] * invN;
        float var  = stats[M + c] * invN - mean * mean;
        float sc   = rsqrtf(var + 1e-5f) * gamma[c];
        stats[2 * M + c] = sc;
        stats[3 * M + c] = beta[c] - mean * sc;
    }
}

template<bool RELU>
__global__ __launch_bounds__(256)
void k_bnapply16(const _Float16* __restrict__ z, const float* __restrict__ stats,
                 _Float16* __restrict__ h, int n, int M) {
    const float* scale = stats + 2 * M;
    const float* shift = stats + 3 * M;
    int total8 = n * (M / 8);
    for (int i = blockIdx.x * 256 + threadIdx.x; i < total8; i += gridDim.x * 256) {
        int c = (i << 3) % M;
        half8 v = *(const half8*)(z + (size_t)i * 8);
        half8 o;
#pragma unroll
        for (int e = 0; e < 8; ++e) {
            float f = (float)v[e] * scale[c + e] + shift[c + e];
            if (RELU) f = fmaxf(f, 0.0f);
            o[e] = (_Float16)f;
        }
        *(half8*)(h + (size_t)i * 8) = o;
    }
}

// ---------------- graph readout (fused final BN) ----------------

__global__ __launch_bounds__(256)
void k_readout_bn(const _Float16* __restrict__ z, const float* __restrict__ stats,
                  const int* __restrict__ gid, float* __restrict__ gsum,
                  int* __restrict__ gcnt, int n) {
    __shared__ float ls[NG * 128];
    __shared__ int   lc[NG];
    for (int i = threadIdx.x; i < NG * 128; i += 256) ls[i] = 0.0f;
    if (threadIdx.x < NG) lc[threadIdx.x] = 0;
    __syncthreads();
    int c  = threadIdx.x & 127;
    int ro = threadIdx.x >> 7;   // 0 or 1
    const float sc = stats[2 * 128 + c];
    const float sh = stats[3 * 128 + c];
    for (int r = blockIdx.x * 2 + ro; r < n; r += gridDim.x * 2) {
        int g = gid[r];
        float v = (float)z[(size_t)r * 128 + c] * sc + sh;
        atomicAdd(&ls[g * 128 + c], v);
        if (c == 0) atomicAdd(&lc[g], 1);
    }
    __syncthreads();
    for (int i = threadIdx.x; i < NG * 128; i += 256) atomicAdd(&gsum[i], ls[i]);
    if (threadIdx.x < NG) atomicAdd(&gcnt[threadIdx.x], lc[threadIdx.x]);
}

__global__ void k_final(const float* __restrict__ gsum, const int* __restrict__ gcnt,
                        float* __restrict__ out) {
    int i = blockIdx.x * 256 + threadIdx.x;
    if (i < NG * 128) {
        int g = i >> 7;
        out[i] = gsum[i] / fmaxf((float)gcnt[g], 1.0f);
    }
}

// ---------------- host ----------------

extern "C" void kernel_launch(void* const* d_in, const int* in_sizes, int n_in,
                              void* d_out, int out_size, void* d_ws, size_t ws_size,
                              hipStream_t stream) {
    const float* x   = (const float*)d_in[0];
    const int*   src = (const int*)d_in[1];
    const int*   dst = (const int*)d_in[2];
    const int*   gid = (const int*)d_in[3];
    const int n = in_sizes[0] / 128;
    const int E = in_sizes[1];

    auto align = [](size_t o) { return (o + 255) & ~(size_t)255; };
    char* ws = (char*)d_ws;
    size_t off = 0;
    const size_t SZ_H  = align((size_t)n * 256 * sizeof(_Float16));  // fp16 N x 256
    const size_t SZ_I  = align((size_t)n * sizeof(int));

    _Float16* h0 = (_Float16*)(ws + off); off += align((size_t)n * 128 * sizeof(_Float16));
    _Float16* P0 = (_Float16*)(ws + off); off += SZ_H;
    _Float16* P1 = (_Float16*)(ws + off); off += SZ_H;
    _Float16* P2 = (_Float16*)(ws + off); off += SZ_H;
    int*   deg  = (int*)(ws + off);   off += SZ_I;
    int*   incl = (int*)(ws + off);   off += SZ_I;
    int*   rowp = (int*)(ws + off);   off += SZ_I;
    int*   cur  = (int*)(ws + off);   off += SZ_I;
    int*   bsum = (int*)(ws + off);   off += 256 * sizeof(int);
    int*   ss   = (int*)(ws + off);   off += align((size_t)E * sizeof(int));
    float* stats= (float*)(ws + off); off += align(4 * 256 * sizeof(float));
    float* gsum = (float*)(ws + off); off += align(NG * 128 * sizeof(float));
    int*   gcnt = (int*)(ws + off);   off += align(NG * sizeof(int));
    _Float16* wh[6];
    for (int i = 0; i < 6; ++i) { wh[i] = (_Float16*)(ws + off); off += align(65536 * sizeof(_Float16)); }

    // ---- casts ----
    k_cast16<<<(n * 128 / 8 + 255) / 256, 256, 0, stream>>>(x, h0, n * 128 / 8);
    const int Ks[3]    = {128, 256, 256};
    const int Mids[3]  = {256, 256, 128};
    const int Mouts[3] = {256, 256, 128};
    for (int L = 0; L < 3; ++L) {
        const int base = 4 + 7 * L;
        int n1 = Mids[L] * Ks[L];
        int n2 = Mouts[L] * Mids[L];
        k_cast16<<<(n1 / 8 + 255) / 256, 256, 0, stream>>>((const float*)d_in[base + 0], wh[2 * L + 0], n1 / 8);
        k_cast16<<<(n2 / 8 + 255) / 256, 256, 0, stream>>>((const float*)d_in[base + 2], wh[2 * L + 1], n2 / 8);
    }

    // ---- CSR build (dst-keyed) ----
    hipMemsetAsync(deg, 0, (size_t)n * sizeof(int), stream);
    k_deg<<<(E + 255) / 256, 256, 0, stream>>>(dst, deg, E);
    int nb = (n + 1023) / 1024;
    k_scan_a<<<nb, 1024, 0, stream>>>(deg, incl, bsum, n);
    k_scan_b<<<1, 1, 0, stream>>>(bsum, nb);
    k_scan_c<<<(n + 255) / 256, 256, 0, stream>>>(incl, deg, bsum, rowp, n);
    hipMemsetAsync(cur, 0, (size_t)n * sizeof(int), stream);
    k_scatter<<<(E + 255) / 256, 256, 0, stream>>>(src, dst, rowp, cur, ss, E);

    // ---- layers ----
    const _Float16* hin = h0;
    for (int L = 0; L < 3; ++L) {
        const int base = 4 + 7 * L;
        const float* b1    = (const float*)d_in[base + 1];
        const float* b2    = (const float*)d_in[base + 3];
        const float* eps   = (const float*)d_in[base + 4];
        const float* gamma = (const float*)d_in[base + 5];
        const float* beta  = (const float*)d_in[base + 6];
        const int K = Ks[L], Mid = Mids[L], Mout = Mouts[L];

        if (K == 128) k_agg16<128><<<(n + 15) / 16, 256, 0, stream>>>(hin, rowp, deg, ss, eps, P1, n);
        else          k_agg16<256><<<(n + 7) / 8,   256, 0, stream>>>(hin, rowp, deg, ss, eps, P1, n);

        dim3 g1((n + 127) / 128, Mid / 128);
        k_gemm16<true><<<g1, 256, 0, stream>>>(P1, wh[2 * L + 0], b1, P2, n, K, Mid);
        dim3 g2((n + 127) / 128, Mout / 128);
        k_gemm16<false><<<g2, 256, 0, stream>>>(P2, wh[2 * L + 1], b2, P1, n, Mid, Mout);

        hipMemsetAsync(stats, 0, 2 * (size_t)Mout * sizeof(float), stream);
        k_bnstats16<<<256, 256, 0, stream>>>(P1, stats, n, Mout);
        k_bnprep<<<1, Mout, 0, stream>>>(stats, gamma, beta, n, Mout);
        if (L < 2) {
            k_bnapply16<true><<<2048, 256, 0, stream>>>(P1, stats, P0, n, Mout);
            hin = P0;
        }
        // L==2: BN fused into readout
    }

    // ---- readout ----
    hipMemsetAsync(gsum, 0, NG * 128 * sizeof(float), stream);
    hipMemsetAsync(gcnt, 0, NG * sizeof(int), stream);
    k_readout_bn<<<256, 256, 0, stream>>>(P1, stats, gid, gsum, gcnt, n);
    k_final<<<4, 256, 0, stream>>>(gsum, gcnt, (float*)d_out);
}